// Round 1
// baseline (1834.980 us; speedup 1.0000x reference)
//
#include <hip/hip_runtime.h>
#include <hip/hip_bf16.h>
#include <math.h>

// Problem constants (from reference): input (16,1024,512) f32, codebook (8192,512) f32
#define N_ROWS 16384
#define DIM    512
#define VOCAB  8192

// GEMM tiling
#define BM 128
#define BN 128
#define BK 32
#define NCHUNK 8          // V split into 8 chunks of 1024 cols
#define TPC 8             // col-tiles (BN wide) per chunk

// ---------------------------------------------------------------------------
// c2[v] = sum(codebook[v]^2)  — one 64-lane wave per row, 4 rows per block
// ---------------------------------------------------------------------------
__global__ void k_c2(const float* __restrict__ cb, float* __restrict__ c2) {
    int row  = blockIdx.x * 4 + (threadIdx.x >> 6);
    int lane = threadIdx.x & 63;
    const float4* p = reinterpret_cast<const float4*>(cb + (size_t)row * DIM);
    float s = 0.f;
#pragma unroll
    for (int i = 0; i < (DIM / 4) / 64; ++i) {   // 2 iters
        float4 v = p[lane + i * 64];
        s += v.x * v.x + v.y * v.y + v.z * v.z + v.w * v.w;
    }
#pragma unroll
    for (int off = 32; off > 0; off >>= 1) s += __shfl_xor(s, off, 64);
    if (lane == 0) c2[row] = s;
}

// ---------------------------------------------------------------------------
// Fused distance GEMM + per-chunk argmin.
// score(n,v) = c2[v] - 2 * dot(x[n], cb[v])   (x2 + sqrt dropped: monotonic)
// grid = (NCHUNK, N_ROWS/BM); each block loops TPC col-tiles of BN within its
// chunk, keeping a running per-row (min,idx) so only N*NCHUNK partials hit ws.
// ---------------------------------------------------------------------------
__launch_bounds__(256, 2)
__global__ void k_gemm_argmin(const float* __restrict__ x,
                              const float* __restrict__ cb,
                              const float* __restrict__ c2,
                              float2* __restrict__ partial) {
    __shared__ float As[BK][BM];   // k-major so fragment reads are contiguous
    __shared__ float Bs[BK][BN];
    const int chunk   = blockIdx.x;
    const int rt      = blockIdx.y;
    const int tid     = threadIdx.x;
    const int tx      = tid & 15;
    const int ty      = tid >> 4;
    const int rowBase = rt * BM;

    float bestS[8];
    int   bestI[8];
#pragma unroll
    for (int i = 0; i < 8; ++i) { bestS[i] = INFINITY; bestI[i] = 0x7fffffff; }

    for (int ct = 0; ct < TPC; ++ct) {
        const int colBase = (chunk * TPC + ct) * BN;
        float acc[8][8];
#pragma unroll
        for (int i = 0; i < 8; ++i)
#pragma unroll
            for (int j = 0; j < 8; ++j) acc[i][j] = 0.f;

        for (int kt = 0; kt < DIM / BK; ++kt) {
            __syncthreads();   // previous tile's LDS reads done before overwrite
#pragma unroll
            for (int p = 0; p < 4; ++p) {
                int idx = p * 256 + tid;
                int r   = idx >> 3;           // 0..127
                int c4  = (idx & 7) * 4;      // 0,4,..,28
                float4 va = *reinterpret_cast<const float4*>(
                    x + (size_t)(rowBase + r) * DIM + kt * BK + c4);
                As[c4 + 0][r] = va.x; As[c4 + 1][r] = va.y;
                As[c4 + 2][r] = va.z; As[c4 + 3][r] = va.w;
                float4 vb = *reinterpret_cast<const float4*>(
                    cb + (size_t)(colBase + r) * DIM + kt * BK + c4);
                Bs[c4 + 0][r] = vb.x; Bs[c4 + 1][r] = vb.y;
                Bs[c4 + 2][r] = vb.z; Bs[c4 + 3][r] = vb.w;
            }
            __syncthreads();
#pragma unroll
            for (int kk = 0; kk < BK; ++kk) {
                float a[8], b[8];
                *reinterpret_cast<float4*>(&a[0]) =
                    *reinterpret_cast<const float4*>(&As[kk][ty * 8]);
                *reinterpret_cast<float4*>(&a[4]) =
                    *reinterpret_cast<const float4*>(&As[kk][ty * 8 + 4]);
                *reinterpret_cast<float4*>(&b[0]) =
                    *reinterpret_cast<const float4*>(&Bs[kk][tx * 8]);
                *reinterpret_cast<float4*>(&b[4]) =
                    *reinterpret_cast<const float4*>(&Bs[kk][tx * 8 + 4]);
#pragma unroll
                for (int i = 0; i < 8; ++i)
#pragma unroll
                    for (int j = 0; j < 8; ++j)
                        acc[i][j] = fmaf(a[i], b[j], acc[i][j]);
            }
        }

        // Epilogue: per-row argmin over this col-tile, then merge into running best.
        float c2v[8];
#pragma unroll
        for (int j = 0; j < 8; ++j) c2v[j] = c2[colBase + tx * 8 + j];
#pragma unroll
        for (int i = 0; i < 8; ++i) {
            float s  = INFINITY;
            int   si = 0x7fffffff;
#pragma unroll
            for (int j = 0; j < 8; ++j) {      // ascending j => first-min tie-break
                float v  = fmaf(-2.f, acc[i][j], c2v[j]);
                int   vi = colBase + tx * 8 + j;
                if (v < s) { s = v; si = vi; }
            }
            // butterfly min+idx across the 16 lanes covering this row
#pragma unroll
            for (int off = 1; off < 16; off <<= 1) {
                float os = __shfl_xor(s, off, 64);
                int   oi = __shfl_xor(si, off, 64);
                if (os < s || (os == s && oi < si)) { s = os; si = oi; }
            }
            if (s < bestS[i] || (s == bestS[i] && si < bestI[i])) {
                bestS[i] = s; bestI[i] = si;
            }
        }
    }

    if (tx == 0) {
#pragma unroll
        for (int i = 0; i < 8; ++i) {
            int row = rowBase + ty * 8 + i;
            partial[(size_t)row * NCHUNK + chunk] =
                make_float2(bestS[i], __int_as_float(bestI[i]));
        }
    }
}

// ---------------------------------------------------------------------------
// Final per-row reduce over NCHUNK partials; write idx (as float), idx (int),
// and mark used flags. Plain same-value stores to used[] are race-benign.
// ---------------------------------------------------------------------------
__global__ void k_reduce(const float2* __restrict__ partial,
                         float* __restrict__ out_idx_f,
                         int* __restrict__ idx_i,
                         int* __restrict__ used) {
    int n = blockIdx.x * 256 + threadIdx.x;
    if (n >= N_ROWS) return;
    float bs = INFINITY;
    int   bi = 0x7fffffff;
#pragma unroll
    for (int c = 0; c < NCHUNK; ++c) {   // ascending chunk => ascending idx ranges
        float2 p  = partial[(size_t)n * NCHUNK + c];
        int    pi = __float_as_int(p.y);
        if (p.x < bs || (p.x == bs && pi < bi)) { bs = p.x; bi = pi; }
    }
    out_idx_f[n] = (float)bi;
    idx_i[n]     = bi;
    used[bi]     = 1;
}

// new_streak[v] = used ? 0 : streak[v] + 1
__global__ void k_streak(const int* __restrict__ streak_in,
                         const int* __restrict__ used,
                         float* __restrict__ out) {
    int v = blockIdx.x * 256 + threadIdx.x;
    if (v < VOCAB) out[v] = used[v] ? 0.f : (float)(streak_in[v] + 1);
}

// embed[n,:] = codebook[idx[n],:]  — float4 gather, codebook is L2-resident
__global__ void k_gather(const float* __restrict__ cb,
                         const int* __restrict__ idx_i,
                         float* __restrict__ out) {
    size_t t  = (size_t)blockIdx.x * 256 + threadIdx.x;   // one float4 each
    int    n  = (int)(t >> 7);        // DIM/4 = 128 float4 per row
    int    d4 = (int)(t & 127);
    reinterpret_cast<float4*>(out)[t] =
        reinterpret_cast<const float4*>(cb + (size_t)idx_i[n] * DIM)[d4];
}

extern "C" void kernel_launch(void* const* d_in, const int* in_sizes, int n_in,
                              void* d_out, int out_size, void* d_ws, size_t ws_size,
                              hipStream_t stream) {
    const float* x      = (const float*)d_in[0];
    const float* cb     = (const float*)d_in[1];
    const int*   streak = (const int*)d_in[2];

    float* out       = (float*)d_out;
    float* out_embed = out;                          // N_ROWS*DIM
    float* out_idx   = out + (size_t)N_ROWS * DIM;   // N_ROWS
    float* out_strk  = out_idx + N_ROWS;             // VOCAB

    char*   ws    = (char*)d_ws;
    float*  c2    = (float*)ws;                 // 32 KB
    int*    used  = (int*)(ws + 32 * 1024);     // 32 KB
    int*    idx_i = (int*)(ws + 64 * 1024);     // 64 KB
    float2* part  = (float2*)(ws + 128 * 1024); // 1 MB  (N_ROWS * NCHUNK * 8B)

    hipMemsetAsync(used, 0, VOCAB * sizeof(int), stream);
    k_c2<<<VOCAB / 4, 256, 0, stream>>>(cb, c2);
    k_gemm_argmin<<<dim3(NCHUNK, N_ROWS / BM), 256, 0, stream>>>(x, cb, c2, part);
    k_reduce<<<N_ROWS / 256, 256, 0, stream>>>(part, out_idx, idx_i, used);
    k_streak<<<VOCAB / 256, 256, 0, stream>>>(streak, used, out_strk);
    k_gather<<<(N_ROWS * DIM / 4) / 256, 256, 0, stream>>>(cb, idx_i, out_embed);
}

// Round 2
// 521.089 us; speedup vs baseline: 3.5214x; 3.5214x over previous
//
#include <hip/hip_runtime.h>
#include <hip/hip_bf16.h>
#include <math.h>

// Problem: input (16,1024,512) f32, codebook (8192,512) f32
#define N_ROWS 16384
#define DIM    512
#define VOCAB  8192

typedef __attribute__((ext_vector_type(8))) short short8;
typedef __attribute__((ext_vector_type(4))) float f32x4;

__device__ inline unsigned short f2bf(float f) {      // RNE f32 -> bf16 bits
    unsigned u = __float_as_uint(f);
    u += 0x7fff + ((u >> 16) & 1);
    return (unsigned short)(u >> 16);
}
__device__ inline float bf2f(unsigned short b) {
    return __uint_as_float(((unsigned)b) << 16);
}

__device__ inline void gload16(const void* g, void* l) {
    __builtin_amdgcn_global_load_lds(
        (const __attribute__((address_space(1))) void*)g,
        (__attribute__((address_space(3))) void*)l, 16, 0, 0);
}

// ---------------------------------------------------------------------------
// Split fp32 -> bf16 (hi) + bf16 (lo = bf16(x - hi)); 4 elems/thread
// ---------------------------------------------------------------------------
__global__ void k_split(const float* __restrict__ in, unsigned short* __restrict__ hi,
                        unsigned short* __restrict__ lo, int n4) {
    int t = blockIdx.x * 256 + threadIdx.x;
    if (t >= n4) return;
    float4 v = reinterpret_cast<const float4*>(in)[t];
    ushort4 h, l;
    h.x = f2bf(v.x); l.x = f2bf(v.x - bf2f(h.x));
    h.y = f2bf(v.y); l.y = f2bf(v.y - bf2f(h.y));
    h.z = f2bf(v.z); l.z = f2bf(v.z - bf2f(h.z));
    h.w = f2bf(v.w); l.w = f2bf(v.w - bf2f(h.w));
    reinterpret_cast<ushort4*>(hi)[t] = h;
    reinterpret_cast<ushort4*>(lo)[t] = l;
}

// ---------------------------------------------------------------------------
// c2[v] = sum(codebook[v]^2) fp32 (validated in round 1)
// ---------------------------------------------------------------------------
__global__ void k_c2(const float* __restrict__ cb, float* __restrict__ c2) {
    int row  = blockIdx.x * 4 + (threadIdx.x >> 6);
    int lane = threadIdx.x & 63;
    const float4* p = reinterpret_cast<const float4*>(cb + (size_t)row * DIM);
    float s = 0.f;
#pragma unroll
    for (int i = 0; i < 2; ++i) {
        float4 v = p[lane + i * 64];
        s += v.x * v.x + v.y * v.y + v.z * v.z + v.w * v.w;
    }
#pragma unroll
    for (int off = 32; off > 0; off >>= 1) s += __shfl_xor(s, off, 64);
    if (lane == 0) c2[row] = s;
}

// ---------------------------------------------------------------------------
// bf16 MFMA GEMM (virtual K = 1536: hi*hi, hi*lo, lo*hi) + fused per-tile
// top-2 argmin epilogue. 128x128 tile, BK=64, 4 waves of 32 rows x 128 cols.
// LDS tiles [128 rows][64 bf16] with XOR swizzle (byte ^= (row&7)<<4) applied
// via pre-swizzled global source (linear global_load_lds dest) + swizzled read.
// ---------------------------------------------------------------------------
__launch_bounds__(256, 2)
__global__ void k_mfma_argmin(const unsigned short* __restrict__ xhi,
                              const unsigned short* __restrict__ xlo,
                              const unsigned short* __restrict__ cbhi,
                              const unsigned short* __restrict__ cblo,
                              const float* __restrict__ c2,
                              float4* __restrict__ part) {
    __shared__ __align__(16) char As[128 * 128];   // 16 KB
    __shared__ __align__(16) char Bs[128 * 128];   // 16 KB
    const int tid  = threadIdx.x;
    const int w    = tid >> 6;
    const int lane = tid & 63;
    const int l15  = lane & 15;
    const int lg   = lane >> 4;
    const int rowBase = blockIdx.y * 128;
    const int colBase = blockIdx.x * 128;

    f32x4 acc[2][8];
#pragma unroll
    for (int mi = 0; mi < 2; ++mi)
#pragma unroll
        for (int nj = 0; nj < 8; ++nj) acc[mi][nj] = (f32x4)0.f;

    // staging constants: chunk = 1024B = 8 rows of 128B; lane covers
    // physical (r = 8*chunk + lane>>3, slot = lane&7); source slot ^= row&7
    const int r8     = lane >> 3;
    const int srcoff = ((lane & 7) ^ r8) << 4;

    for (int kt = 0; kt < 24; ++kt) {
        const int phase = kt >> 3;            // 0: hi*hi  1: hi*lo  2: lo*hi
        const int kb    = (kt & 7) << 7;      // byte offset within 1024B row
        const char* Asrc = (const char*)(phase == 2 ? xlo : xhi);
        const char* Bsrc = (const char*)(phase == 1 ? cblo : cbhi);
        if (kt) __syncthreads();
#pragma unroll
        for (int t = 0; t < 4; ++t) {
            int i  = 4 * w + t;               // chunk index 0..15
            int r0 = 8 * i;
            gload16(Asrc + (size_t)(rowBase + r0 + r8) * 1024 + kb + srcoff,
                    As + 1024 * i);
            gload16(Bsrc + (size_t)(colBase + r0 + r8) * 1024 + kb + srcoff,
                    Bs + 1024 * i);
        }
        __syncthreads();
#pragma unroll
        for (int kk = 0; kk < 2; ++kk) {
            const int ob = kk * 64 + lg * 16;
            short8 a[2], b[8];
#pragma unroll
            for (int mi = 0; mi < 2; ++mi) {
                int r = w * 32 + mi * 16 + l15;
                a[mi] = *(const short8*)(As + r * 128 + (ob ^ ((r & 7) << 4)));
            }
#pragma unroll
            for (int nj = 0; nj < 8; ++nj) {
                int r = nj * 16 + l15;
                b[nj] = *(const short8*)(Bs + r * 128 + (ob ^ ((r & 7) << 4)));
            }
#pragma unroll
            for (int mi = 0; mi < 2; ++mi)
#pragma unroll
                for (int nj = 0; nj < 8; ++nj)
                    acc[mi][nj] = __builtin_amdgcn_mfma_f32_16x16x32_bf16(
                        a[mi], b[nj], acc[mi][nj], 0, 0, 0);
        }
    }

    // Epilogue: score = c2[v] - 2*dot; per-row top-2 over this block's 128 cols.
    // C layout (m89): col = lane&15, row = 4*(lane>>4) + reg.
    float c2v[8];
#pragma unroll
    for (int nj = 0; nj < 8; ++nj) c2v[nj] = c2[colBase + nj * 16 + l15];

#pragma unroll
    for (int mi = 0; mi < 2; ++mi) {
#pragma unroll
        for (int reg = 0; reg < 4; ++reg) {
            float s1 = INFINITY, s2 = INFINITY;
            int   i1 = 0x7fffffff, i2 = 0x7fffffff;
#pragma unroll
            for (int nj = 0; nj < 8; ++nj) {
                float s = fmaf(-2.f, acc[mi][nj][reg], c2v[nj]);
                int   v = colBase + nj * 16 + l15;
                if (s < s1 || (s == s1 && v < i1)) { s2 = s1; i2 = i1; s1 = s; i1 = v; }
                else if (s < s2 || (s == s2 && v < i2)) { s2 = s; i2 = v; }
            }
#pragma unroll
            for (int off = 1; off < 16; off <<= 1) {   // butterfly over 16 cols-lanes
                float t1 = __shfl_xor(s1, off, 64); int j1 = __shfl_xor(i1, off, 64);
                float t2 = __shfl_xor(s2, off, 64); int j2 = __shfl_xor(i2, off, 64);
                bool bfirst = (t1 < s1) || (t1 == s1 && j1 < i1);
                if (bfirst) {
                    float n2s; int n2i;
                    if (s1 < t2 || (s1 == t2 && i1 < j2)) { n2s = s1; n2i = i1; }
                    else                                   { n2s = t2; n2i = j2; }
                    s1 = t1; i1 = j1; s2 = n2s; i2 = n2i;
                } else {
                    if (t1 < s2 || (t1 == s2 && j1 < i2)) { s2 = t1; i2 = j1; }
                }
            }
            if (l15 == 0) {
                int row = rowBase + w * 32 + mi * 16 + 4 * lg + reg;
                part[(size_t)row * 64 + blockIdx.x] =
                    make_float4(s1, __int_as_float(i1), s2, __int_as_float(i2));
            }
        }
    }
}

// ---------------------------------------------------------------------------
// Per-row final: approx global min over 64 tile-top2s; exact fp32 rescore of
// every candidate within min+1.0 (margin >> any possible bf16-split error);
// lexicographic (score, idx) min == reference argmin semantics.
// ---------------------------------------------------------------------------
__global__ void k_select(const float4* __restrict__ part,
                         const float* __restrict__ x,
                         const float* __restrict__ cb,
                         const float* __restrict__ c2,
                         float* __restrict__ out_idx_f,
                         int* __restrict__ idx_i,
                         int* __restrict__ used) {
    int wv   = threadIdx.x >> 6;
    int lane = threadIdx.x & 63;
    int row  = blockIdx.x * 4 + wv;
    float4 p = part[(size_t)row * 64 + lane];
    float s1 = p.x; int i1 = __float_as_int(p.y);
    float s2 = p.z; int i2 = __float_as_int(p.w);
    float gm = s1;
#pragma unroll
    for (int off = 1; off < 64; off <<= 1) gm = fminf(gm, __shfl_xor(gm, off, 64));
    float thresh = gm + 1.0f;
    unsigned long long m1 = __ballot(s1 <= thresh);
    unsigned long long m2 = __ballot(s2 <= thresh);
    float be = INFINITY; int bi = 0x7fffffff;
    const float4* xr = reinterpret_cast<const float4*>(x + (size_t)row * DIM);
    while (m1 | m2) {
        int vi;
        if (m1) { int t = __ffsll(m1) - 1; m1 &= m1 - 1; vi = __shfl(i1, t); }
        else    { int t = __ffsll(m2) - 1; m2 &= m2 - 1; vi = __shfl(i2, t); }
        const float4* cr = reinterpret_cast<const float4*>(cb + (size_t)vi * DIM);
        float d = 0.f;
#pragma unroll
        for (int q = 0; q < 2; ++q) {
            float4 a = xr[q * 64 + lane];
            float4 b = cr[q * 64 + lane];
            d += a.x * b.x + a.y * b.y + a.z * b.z + a.w * b.w;
        }
#pragma unroll
        for (int off = 1; off < 64; off <<= 1) d += __shfl_xor(d, off, 64);
        float se = c2[vi] - 2.f * d;
        if (se < be || (se == be && vi < bi)) { be = se; bi = vi; }
    }
    if (lane == 0) {
        out_idx_f[row] = (float)bi;
        idx_i[row]     = bi;
        used[bi]       = 1;
    }
}

// new_streak[v] = used ? 0 : streak[v] + 1
__global__ void k_streak(const int* __restrict__ streak_in,
                         const int* __restrict__ used,
                         float* __restrict__ out) {
    int v = blockIdx.x * 256 + threadIdx.x;
    if (v < VOCAB) out[v] = used[v] ? 0.f : (float)(streak_in[v] + 1);
}

// embed[n,:] = codebook[idx[n],:]
__global__ void k_gather(const float* __restrict__ cb,
                         const int* __restrict__ idx_i,
                         float* __restrict__ out) {
    size_t t  = (size_t)blockIdx.x * 256 + threadIdx.x;
    int    n  = (int)(t >> 7);
    int    d4 = (int)(t & 127);
    reinterpret_cast<float4*>(out)[t] =
        reinterpret_cast<const float4*>(cb + (size_t)idx_i[n] * DIM)[d4];
}

extern "C" void kernel_launch(void* const* d_in, const int* in_sizes, int n_in,
                              void* d_out, int out_size, void* d_ws, size_t ws_size,
                              hipStream_t stream) {
    const float* x      = (const float*)d_in[0];
    const float* cb     = (const float*)d_in[1];
    const int*   streak = (const int*)d_in[2];

    float* out       = (float*)d_out;
    float* out_embed = out;
    float* out_idx   = out + (size_t)N_ROWS * DIM;
    float* out_strk  = out_idx + N_ROWS;

    char* ws = (char*)d_ws;
    unsigned short* xhi  = (unsigned short*)(ws);                         // 16 MB
    unsigned short* xlo  = (unsigned short*)(ws + (16u << 20));           // 16 MB
    unsigned short* cbhi = (unsigned short*)(ws + (32u << 20));           // 8 MB
    unsigned short* cblo = (unsigned short*)(ws + (40u << 20));           // 8 MB
    float* c2    = (float*)(ws + (48u << 20));                            // 32 KB
    int*   idx_i = (int*)(ws + (48u << 20) + (1u << 16));                 // 64 KB
    int*   used  = (int*)(ws + (48u << 20) + (2u << 16));                 // 32 KB
    float4* part = (float4*)(ws + (49u << 20));                           // 16 MB

    hipMemsetAsync(used, 0, VOCAB * sizeof(int), stream);
    k_split<<<(N_ROWS * DIM / 4) / 256, 256, 0, stream>>>(x, xhi, xlo, N_ROWS * DIM / 4);
    k_split<<<(VOCAB * DIM / 4) / 256, 256, 0, stream>>>(cb, cbhi, cblo, VOCAB * DIM / 4);
    k_c2<<<VOCAB / 4, 256, 0, stream>>>(cb, c2);
    k_mfma_argmin<<<dim3(VOCAB / 128, N_ROWS / 128), 256, 0, stream>>>(
        xhi, xlo, cbhi, cblo, c2, part);
    k_select<<<N_ROWS / 4, 256, 0, stream>>>(part, x, cb, c2, out_idx, idx_i, used);
    k_streak<<<VOCAB / 256, 256, 0, stream>>>(streak, used, out_strk);
    k_gather<<<(N_ROWS * DIM / 4) / 256, 256, 0, stream>>>(cb, idx_i, out_embed);
}